// Round 6
// baseline (287.079 us; speedup 1.0000x reference)
//
#include <hip/hip_runtime.h>
#include <hip/hip_bf16.h>

#define B_ 64
#define S_ 1024
#define H_ 256
#define E_ 256

#define EG_ 32          // e-columns per block
#define LDSB_ST 264     // bf16 stride for B panel (256 data + 8 pad)
#define CH_ 128         // rows per s-chunk (8 waves x 16)
#define NCH_ 8          // s-chunks per batch

typedef __attribute__((ext_vector_type(8))) __bf16 bf16x8;
typedef __attribute__((ext_vector_type(4))) float f32x4;

// Single fused kernel. Block = (batch b, 32 e-columns); 512 thr = 8 waves.
// Zero inter-block communication, zero workspace, drain-free chunk loop.
__global__ __launch_bounds__(512, 4) void k_all(
        const float* __restrict__ alpha, const float* __restrict__ beta,
        const float* __restrict__ embed, const float* __restrict__ mask,
        const float* __restrict__ Wb,    const float* __restrict__ bb,
        const float* __restrict__ Wa,    const float* __restrict__ ba,
        float* __restrict__ t) {
    __shared__ __bf16 ldsB[EG_ * LDSB_ST];   // 16.5 KB stationary B panel
    __shared__ float wsLds[S_];              // w[b, :]
    __shared__ float ivLds[S_];              // 1/(w-suffix + eps)
    __shared__ float red[2][8 * EG_];        // double-buffered wave column totals
    __shared__ float run[2][EG_];            // double-buffered cross-chunk carry
    __shared__ float wsum[4];

    const int tid = threadIdx.x;
    const int wv = tid >> 6, lane = tid & 63;
    const int l15 = lane & 15, q = lane >> 4;
    const int blk = blockIdx.x;
    // XCD co-location: the 8 e-group blocks of a batch share blk%8 -> one XCD L2
    const int b  = (blk & 7) * 8 + (blk >> 6);   // 0..63
    const int eg = (blk >> 3) & 7;               // 0..7

    // ---- stage own Wb panel fp32 -> bf16 -> LDS (k0 deleted) ----
    {
        const int e = tid >> 4, kq = (tid & 15) * 16;
        const float4* src = (const float4*)(Wb + (size_t)(eg * EG_ + e) * H_ + kq);
        float4 v0 = src[0], v1 = src[1], v2 = src[2], v3 = src[3];
        bf16x8 p0, p1;
        p0[0]=(__bf16)v0.x; p0[1]=(__bf16)v0.y; p0[2]=(__bf16)v0.z; p0[3]=(__bf16)v0.w;
        p0[4]=(__bf16)v1.x; p0[5]=(__bf16)v1.y; p0[6]=(__bf16)v1.z; p0[7]=(__bf16)v1.w;
        p1[0]=(__bf16)v2.x; p1[1]=(__bf16)v2.y; p1[2]=(__bf16)v2.z; p1[3]=(__bf16)v2.w;
        p1[4]=(__bf16)v3.x; p1[5]=(__bf16)v3.y; p1[6]=(__bf16)v3.z; p1[7]=(__bf16)v3.w;
        *(bf16x8*)(ldsB + e * LDSB_ST + kq)     = p0;
        *(bf16x8*)(ldsB + e * LDSB_ST + kq + 8) = p1;
    }

    // ---- phase W (redundant per block; alpha via XCD-local L2):
    //      16 lanes/row, coalesced 256B/row segments, 4 rows per wave-pass ----
    {
        const int rsub = lane >> 4, pcl = lane & 15;
        const float4* Wa4 = (const float4*)Wa;
        float4 wa0 = Wa4[pcl], wa1 = Wa4[pcl + 16],
               wa2 = Wa4[pcl + 32], wa3 = Wa4[pcl + 48];
        const float ba0 = ba[0];
        #pragma unroll 2
        for (int ps = 0; ps < 32; ++ps) {
            const int row = wv * 128 + ps * 4 + rsub;
            const float4* ap = (const float4*)(alpha + ((size_t)b * S_ + row) * H_);
            float4 x0 = ap[pcl], x1 = ap[pcl + 16], x2 = ap[pcl + 32], x3 = ap[pcl + 48];
            float p = x0.x*wa0.x + x0.y*wa0.y + x0.z*wa0.z + x0.w*wa0.w
                    + x1.x*wa1.x + x1.y*wa1.y + x1.z*wa1.z + x1.w*wa1.w
                    + x2.x*wa2.x + x2.y*wa2.y + x2.z*wa2.z + x2.w*wa2.w
                    + x3.x*wa3.x + x3.y*wa3.y + x3.z*wa3.z + x3.w*wa3.w;
            p += __shfl_xor(p, 1, 64);
            p += __shfl_xor(p, 2, 64);
            p += __shfl_xor(p, 4, 64);
            p += __shfl_xor(p, 8, 64);
            if (pcl == 0) wsLds[row] = __expf(p + ba0) * mask[b * S_ + row];
        }
    }
    if (tid < 64) run[tid >> 5][tid & 31] = 0.f;
    __syncthreads();

    // ---- in-LDS suffix scan of w -> ivLds (256 threads, 4 elems each) ----
    {
        float w0 = 0, w1 = 0, w2 = 0, w3 = 0, tot = 0, suf = 0;
        const int sl = tid & 63, sw = tid >> 6;
        if (tid < 256) {
            w0 = wsLds[tid * 4];     w1 = wsLds[tid * 4 + 1];
            w2 = wsLds[tid * 4 + 2]; w3 = wsLds[tid * 4 + 3];
            tot = w0 + w1 + w2 + w3;
            suf = tot;
            #pragma unroll
            for (int off = 1; off < 64; off <<= 1) {
                float o = __shfl_down(suf, off, 64);
                if (sl + off < 64) suf += o;
            }
            if (sl == 0) wsum[sw] = suf;
        }
        __syncthreads();
        if (tid < 256) {
            float waveOff = 0.f;
            for (int j = sw + 1; j < 4; ++j) waveOff += wsum[j];
            float after = (suf - tot) + waveOff;
            float s3 = w3 + after, s2 = w2 + s3, s1 = w1 + s2, s0 = w0 + s1;
            ivLds[tid * 4]     = 1.f / (s0 + 1e-10f);
            ivLds[tid * 4 + 1] = 1.f / (s1 + 1e-10f);
            ivLds[tid * 4 + 2] = 1.f / (s2 + 1e-10f);
            ivLds[tid * 4 + 3] = 1.f / (s3 + 1e-10f);
        }
        __syncthreads();
    }

    const float bb0 = bb[eg * EG_ + l15];
    const float bb1 = bb[eg * EG_ + 16 + l15];
    const float* Arow0 = beta + ((size_t)b * S_ + wv * 16 + l15) * H_ + q * 8;
    const size_t ebase = ((size_t)b * S_ + wv * 16 + q * 4) * E_ + eg * EG_;
    const float* E0 = embed + ebase + l15;
    const float* E1 = embed + ebase + 16 + l15;
    float* T0 = t + ebase + l15;
    float* T1 = t + ebase + 16 + l15;

    // prefetch first-half A for the first chunk
    float4 pa[4], pb[4];
    #pragma unroll
    for (int kc = 0; kc < 4; ++kc) {
        pa[kc] = *(const float4*)(Arow0 + (size_t)(NCH_ - 1) * CH_ * H_ + kc * 32);
        pb[kc] = *(const float4*)(Arow0 + (size_t)(NCH_ - 1) * CH_ * H_ + kc * 32 + 4);
    }

    int rb = 0;
    for (int c = NCH_ - 1; c >= 0; --c) {
        const size_t coff = (size_t)c * CH_ * H_;
        const size_t eoff = (size_t)c * CH_ * E_;

        // embed prefetch (lands under the MFMA loop)
        float e0[4], e1[4];
        #pragma unroll
        for (int r = 0; r < 4; ++r) {
            e0[r] = E0[eoff + (size_t)r * E_];
            e1[r] = E1[eoff + (size_t)r * E_];
        }
        // second-half A loads (land under first-half MFMAs)
        float4 ha[4], hb[4];
        #pragma unroll
        for (int kc = 0; kc < 4; ++kc) {
            ha[kc] = *(const float4*)(Arow0 + coff + (kc + 4) * 32);
            hb[kc] = *(const float4*)(Arow0 + coff + (kc + 4) * 32 + 4);
        }

        f32x4 acc0 = {0.f, 0.f, 0.f, 0.f}, acc1 = {0.f, 0.f, 0.f, 0.f};
        #pragma unroll
        for (int kc = 0; kc < 8; ++kc) {
            float4 a0 = (kc < 4) ? pa[kc] : ha[kc - 4];
            float4 a1 = (kc < 4) ? pb[kc] : hb[kc - 4];
            bf16x8 af;
            af[0] = (__bf16)a0.x; af[1] = (__bf16)a0.y;
            af[2] = (__bf16)a0.z; af[3] = (__bf16)a0.w;
            af[4] = (__bf16)a1.x; af[5] = (__bf16)a1.y;
            af[6] = (__bf16)a1.z; af[7] = (__bf16)a1.w;
            bf16x8 bf0 = *(const bf16x8*)(ldsB + l15 * LDSB_ST + kc * 32 + q * 8);
            bf16x8 bf1 = *(const bf16x8*)(ldsB + (16 + l15) * LDSB_ST + kc * 32 + q * 8);
            acc0 = __builtin_amdgcn_mfma_f32_16x16x32_bf16(af, bf0, acc0, 0, 0, 0);
            acc1 = __builtin_amdgcn_mfma_f32_16x16x32_bf16(af, bf1, acc1, 0, 0, 0);
        }

        // cross-chunk A prefetch: stays in flight through the light barrier
        if (c > 0) {
            #pragma unroll
            for (int kc = 0; kc < 4; ++kc) {
                pa[kc] = *(const float4*)(Arow0 + coff - (size_t)CH_ * H_ + kc * 32);
                pb[kc] = *(const float4*)(Arow0 + coff - (size_t)CH_ * H_ + kc * 32 + 4);
            }
        }

        // epilogue: tanh * w * embed, wave-local 16-row suffix
        float wmr[4], iv[4];
        #pragma unroll
        for (int r = 0; r < 4; ++r) {
            wmr[r] = wsLds[c * CH_ + wv * 16 + q * 4 + r];
            iv[r]  = ivLds[c * CH_ + wv * 16 + q * 4 + r];
        }
        float sv0[4], sv1[4];
        {
            float tv[4];
            #pragma unroll
            for (int r = 0; r < 4; ++r) {
                float x = acc0[r] + bb0;
                x = fminf(fmaxf(x, -15.f), 15.f);
                float ex = __expf(2.f * x);
                float th = (ex - 1.f) / (ex + 1.f);
                tv[r] = wmr[r] * th * e0[r];
            }
            float s3 = tv[3], s2 = tv[2] + s3, s1 = tv[1] + s2, s0 = tv[0] + s1;
            float g = s0;
            float g1 = __shfl_down(g, 16, 64);
            float g2 = __shfl_down(g, 32, 64);
            float g3 = __shfl_down(g, 48, 64);
            float addG = (q < 3 ? g1 : 0.f) + (q < 2 ? g2 : 0.f) + (q < 1 ? g3 : 0.f);
            if (q == 0) red[rb][wv * EG_ + l15] = g + addG;
            sv0[0] = s0 + addG; sv0[1] = s1 + addG;
            sv0[2] = s2 + addG; sv0[3] = s3 + addG;
        }
        {
            float tv[4];
            #pragma unroll
            for (int r = 0; r < 4; ++r) {
                float x = acc1[r] + bb1;
                x = fminf(fmaxf(x, -15.f), 15.f);
                float ex = __expf(2.f * x);
                float th = (ex - 1.f) / (ex + 1.f);
                tv[r] = wmr[r] * th * e1[r];
            }
            float s3 = tv[3], s2 = tv[2] + s3, s1 = tv[1] + s2, s0 = tv[0] + s1;
            float g = s0;
            float g1 = __shfl_down(g, 16, 64);
            float g2 = __shfl_down(g, 32, 64);
            float g3 = __shfl_down(g, 48, 64);
            float addG = (q < 3 ? g1 : 0.f) + (q < 2 ? g2 : 0.f) + (q < 1 ? g3 : 0.f);
            if (q == 0) red[rb][wv * EG_ + 16 + l15] = g + addG;
            sv1[0] = s0 + addG; sv1[1] = s1 + addG;
            sv1[2] = s2 + addG; sv1[3] = s3 + addG;
        }

        // LIGHT barrier: drain LDS (lgkmcnt) only; global loads/stores keep flying
        asm volatile("s_waitcnt lgkmcnt(0)" ::: "memory");
        __builtin_amdgcn_s_barrier();
        __builtin_amdgcn_sched_barrier(0);

        // gather later-wave totals + carry; final store (overlaps next chunk)
        float nr0, nr1;
        {
            const float rn = run[rb][l15];
            float later = rn, tot = 0.f;
            #pragma unroll
            for (int w2 = 0; w2 < 8; ++w2) {
                float v = red[rb][w2 * EG_ + l15];
                tot += v;
                if (w2 > wv) later += v;
            }
            nr0 = rn + tot;
            #pragma unroll
            for (int r = 0; r < 4; ++r)
                T0[eoff + (size_t)r * E_] = (sv0[r] + later) * iv[r];
        }
        {
            const float rn = run[rb][16 + l15];
            float later = rn, tot = 0.f;
            #pragma unroll
            for (int w2 = 0; w2 < 8; ++w2) {
                float v = red[rb][w2 * EG_ + 16 + l15];
                tot += v;
                if (w2 > wv) later += v;
            }
            nr1 = rn + tot;
            #pragma unroll
            for (int r = 0; r < 4; ++r)
                T1[eoff + (size_t)r * E_] = (sv1[r] + later) * iv[r];
        }
        if (wv == 0 && q == 0) {       // write next chunk's carry (other buffer)
            run[rb ^ 1][l15] = nr0;
            run[rb ^ 1][16 + l15] = nr1;
        }
        rb ^= 1;
    }
}

extern "C" void kernel_launch(void* const* d_in, const int* in_sizes, int n_in,
                              void* d_out, int out_size, void* d_ws, size_t ws_size,
                              hipStream_t stream) {
    const float* alpha = (const float*)d_in[0];
    const float* beta  = (const float*)d_in[1];
    const float* embed = (const float*)d_in[2];
    const float* mask  = (const float*)d_in[3];
    const float* Wb    = (const float*)d_in[4];
    const float* bbp   = (const float*)d_in[5];
    const float* Wa    = (const float*)d_in[6];
    const float* bap   = (const float*)d_in[7];

    k_all<<<B_ * (E_ / EG_), 512, 0, stream>>>(alpha, beta, embed, mask,
                                               Wb, bbp, Wa, bap, (float*)d_out);
}

// Round 7
// 283.051 us; speedup vs baseline: 1.0142x; 1.0142x over previous
//
#include <hip/hip_runtime.h>
#include <hip/hip_bf16.h>

#define B_ 64
#define S_ 1024
#define H_ 256
#define E_ 256

#define EG_ 32          // e-columns per k2 block
#define LDSB_ST 264     // bf16 stride for B panel (256 data + 8 pad)

typedef __attribute__((ext_vector_type(8))) __bf16 bf16x8;
typedef __attribute__((ext_vector_type(4))) __bf16 bf16x4;
typedef __attribute__((ext_vector_type(4))) float f32x4;

// ---- k0: w[m] = exp(alpha[m,:].Wa + ba)*mask[m], fully coalesced
//      (16 lanes/row: each instr reads 4 rows x 256B contiguous = 1KB);
//      blocks 0..63 also convert Wb fp32 -> bf16.
__global__ __launch_bounds__(256) void k0_prep(
        const float* __restrict__ alpha, const float* __restrict__ mask,
        const float* __restrict__ Wa,    const float* __restrict__ ba,
        const float* __restrict__ Wb,    __bf16* __restrict__ WbBf,
        float* __restrict__ w) {
    const int tid = threadIdx.x, blk = blockIdx.x;
    if (blk < 64) {   // 64 blocks x 256 thr x 1 float4 == 16384 float4 of Wb
        int i = blk * 256 + tid;
        float4 v = ((const float4*)Wb)[i];
        bf16x4 bv;
        bv[0] = (__bf16)v.x; bv[1] = (__bf16)v.y;
        bv[2] = (__bf16)v.z; bv[3] = (__bf16)v.w;
        ((bf16x4*)WbBf)[i] = bv;
    }
    const int wv = tid >> 6, lane = tid & 63;
    const int rsub = lane >> 4, pcl = lane & 15;
    const float4* Wa4 = (const float4*)Wa;
    float4 wa0 = Wa4[pcl], wa1 = Wa4[pcl + 16],
           wa2 = Wa4[pcl + 32], wa3 = Wa4[pcl + 48];
    const float ba0 = ba[0];
    #pragma unroll 2
    for (int ps = 0; ps < 8; ++ps) {
        const int m = blk * 128 + ps * 16 + wv * 4 + rsub;
        const float4* ap = (const float4*)(alpha + (size_t)m * H_);
        float4 x0 = ap[pcl], x1 = ap[pcl + 16], x2 = ap[pcl + 32], x3 = ap[pcl + 48];
        float p = x0.x*wa0.x + x0.y*wa0.y + x0.z*wa0.z + x0.w*wa0.w
                + x1.x*wa1.x + x1.y*wa1.y + x1.z*wa1.z + x1.w*wa1.w
                + x2.x*wa2.x + x2.y*wa2.y + x2.z*wa2.z + x2.w*wa2.w
                + x3.x*wa3.x + x3.y*wa3.y + x3.z*wa3.z + x3.w*wa3.w;
        p += __shfl_xor(p, 1, 64);
        p += __shfl_xor(p, 2, 64);
        p += __shfl_xor(p, 4, 64);
        p += __shfl_xor(p, 8, 64);
        if (pcl == 0) w[m] = __expf(p + ba0) * mask[m];
    }
}

// ---- k2: block = (batch b, 32 e-cols); 8 waves; wave wv owns CONTIGUOUS rows
//      [wv*128, wv*128+128). Scan carry lives in registers (shfl broadcast of
//      tile totals) -> ZERO barriers in the main loop; suffix values for all
//      128x32 outputs held in regs; ONE barrier to exchange per-wave totals;
//      final t written once at the end.
__global__ __launch_bounds__(512, 4) void k2_main(
        const float* __restrict__ beta, const float* __restrict__ embed,
        const __bf16* __restrict__ WbBf, const float* __restrict__ bb,
        const float* __restrict__ w, float* __restrict__ t) {
    __shared__ __bf16 ldsB[EG_ * LDSB_ST];   // 16.5 KB stationary B panel
    __shared__ float wsLds[S_];              // w[b, :]
    __shared__ float ivLds[S_];              // 1/(w-suffix + eps)
    __shared__ float red[8][EG_];            // per-wave column totals
    __shared__ float wsum[4];

    const int tid = threadIdx.x;
    const int wv = tid >> 6, lane = tid & 63;
    const int l15 = lane & 15, q = lane >> 4;
    const int blk = blockIdx.x;
    // XCD co-location: the 8 e-group blocks of a batch share blk%8 -> one XCD L2
    const int b  = (blk & 7) * 8 + (blk >> 6);   // 0..63
    const int eg = (blk >> 3) & 7;               // 0..7

    // ---- stage B panel (bf16, pre-converted) + w ----
    {
        const int e = tid >> 4, kq = (tid & 15) * 16;
        const __bf16* src = WbBf + (size_t)(eg * EG_ + e) * H_ + kq;
        *(bf16x8*)(ldsB + e * LDSB_ST + kq)     = *(const bf16x8*)(src);
        *(bf16x8*)(ldsB + e * LDSB_ST + kq + 8) = *(const bf16x8*)(src + 8);
    }
    if (tid < 256)
        *(float4*)(wsLds + tid * 4) = *(const float4*)(w + b * S_ + tid * 4);
    __syncthreads();

    // ---- in-LDS suffix scan of w -> ivLds (256 threads, 4 elems each) ----
    {
        float w0 = 0, w1 = 0, w2 = 0, w3 = 0, tot = 0, suf = 0;
        const int sl = tid & 63, sw = tid >> 6;
        if (tid < 256) {
            w0 = wsLds[tid * 4];     w1 = wsLds[tid * 4 + 1];
            w2 = wsLds[tid * 4 + 2]; w3 = wsLds[tid * 4 + 3];
            tot = w0 + w1 + w2 + w3;
            suf = tot;
            #pragma unroll
            for (int off = 1; off < 64; off <<= 1) {
                float o = __shfl_down(suf, off, 64);
                if (sl + off < 64) suf += o;
            }
            if (sl == 0) wsum[sw] = suf;
        }
        __syncthreads();
        if (tid < 256) {
            float waveOff = 0.f;
            for (int j = sw + 1; j < 4; ++j) waveOff += wsum[j];
            float after = (suf - tot) + waveOff;
            float s3 = w3 + after, s2 = w2 + s3, s1 = w1 + s2, s0 = w0 + s1;
            ivLds[tid * 4]     = 1.f / (s0 + 1e-10f);
            ivLds[tid * 4 + 1] = 1.f / (s1 + 1e-10f);
            ivLds[tid * 4 + 2] = 1.f / (s2 + 1e-10f);
            ivLds[tid * 4 + 3] = 1.f / (s3 + 1e-10f);
        }
        __syncthreads();
    }

    const float bb0 = bb[eg * EG_ + l15];
    const float bb1 = bb[eg * EG_ + 16 + l15];
    const float* Arow = beta + ((size_t)b * S_ + wv * 128 + l15) * H_ + q * 8;
    const size_t ebase = ((size_t)b * S_ + wv * 128 + q * 4) * E_ + eg * EG_;
    const float* E0 = embed + ebase + l15;
    const float* E1 = E0 + 16;
    float* T0 = t + ebase + l15;
    float* T1 = T0 + 16;

    float sv0[8][4], sv1[8][4];   // statically indexed -> registers
    float run0 = 0.f, run1 = 0.f; // register scan carry (later tiles of this wave)

    // ---- main loop: 8 sub-tiles descending, NO barriers ----
    #pragma unroll
    for (int si = 0; si < 8; ++si) {
        const int st = 7 - si;
        const size_t aoff = (size_t)st * 16 * H_;
        const size_t eoff = (size_t)st * 16 * E_;

        // embed loads (land under the MFMA chain)
        float e0[4], e1[4];
        #pragma unroll
        for (int r = 0; r < 4; ++r) {
            e0[r] = E0[eoff + (size_t)r * E_];
            e1[r] = E1[eoff + (size_t)r * E_];
        }

        f32x4 acc0 = {0.f, 0.f, 0.f, 0.f}, acc1 = {0.f, 0.f, 0.f, 0.f};
        #pragma unroll
        for (int kc = 0; kc < 8; ++kc) {
            float4 a0 = *(const float4*)(Arow + aoff + kc * 32);
            float4 a1 = *(const float4*)(Arow + aoff + kc * 32 + 4);
            bf16x8 af;
            af[0] = (__bf16)a0.x; af[1] = (__bf16)a0.y;
            af[2] = (__bf16)a0.z; af[3] = (__bf16)a0.w;
            af[4] = (__bf16)a1.x; af[5] = (__bf16)a1.y;
            af[6] = (__bf16)a1.z; af[7] = (__bf16)a1.w;
            bf16x8 bf0 = *(const bf16x8*)(ldsB + l15 * LDSB_ST + kc * 32 + q * 8);
            bf16x8 bf1 = *(const bf16x8*)(ldsB + (16 + l15) * LDSB_ST + kc * 32 + q * 8);
            acc0 = __builtin_amdgcn_mfma_f32_16x16x32_bf16(af, bf0, acc0, 0, 0, 0);
            acc1 = __builtin_amdgcn_mfma_f32_16x16x32_bf16(af, bf1, acc1, 0, 0, 0);
        }

        // epilogue: tanh * w * embed; 16-row suffix; register carry
        float wmr[4];
        #pragma unroll
        for (int r = 0; r < 4; ++r)
            wmr[r] = wsLds[wv * 128 + st * 16 + q * 4 + r];
        {
            float tv[4];
            #pragma unroll
            for (int r = 0; r < 4; ++r) {
                float x = acc0[r] + bb0;
                x = fminf(fmaxf(x, -15.f), 15.f);
                float ex = __expf(2.f * x);
                float th = (ex - 1.f) / (ex + 1.f);
                tv[r] = wmr[r] * th * e0[r];
            }
            float s3 = tv[3], s2 = tv[2] + s3, s1 = tv[1] + s2, s0 = tv[0] + s1;
            float g = s0;
            float g1 = __shfl_down(g, 16, 64);
            float g2 = __shfl_down(g, 32, 64);
            float g3 = __shfl_down(g, 48, 64);
            float addG = (q < 3 ? g1 : 0.f) + (q < 2 ? g2 : 0.f) + (q < 1 ? g3 : 0.f);
            float top = s0 + addG;                 // at q==0: full 16-row col sum
            float tot = __shfl(top, l15, 64);      // broadcast from lane l15 (q=0)
            sv0[si][0] = s0 + addG + run0;
            sv0[si][1] = s1 + addG + run0;
            sv0[si][2] = s2 + addG + run0;
            sv0[si][3] = s3 + addG + run0;
            run0 += tot;
        }
        {
            float tv[4];
            #pragma unroll
            for (int r = 0; r < 4; ++r) {
                float x = acc1[r] + bb1;
                x = fminf(fmaxf(x, -15.f), 15.f);
                float ex = __expf(2.f * x);
                float th = (ex - 1.f) / (ex + 1.f);
                tv[r] = wmr[r] * th * e1[r];
            }
            float s3 = tv[3], s2 = tv[2] + s3, s1 = tv[1] + s2, s0 = tv[0] + s1;
            float g = s0;
            float g1 = __shfl_down(g, 16, 64);
            float g2 = __shfl_down(g, 32, 64);
            float g3 = __shfl_down(g, 48, 64);
            float addG = (q < 3 ? g1 : 0.f) + (q < 2 ? g2 : 0.f) + (q < 1 ? g3 : 0.f);
            float top = s0 + addG;
            float tot = __shfl(top, l15, 64);
            sv1[si][0] = s0 + addG + run1;
            sv1[si][1] = s1 + addG + run1;
            sv1[si][2] = s2 + addG + run1;
            sv1[si][3] = s3 + addG + run1;
            run1 += tot;
        }
    }

    // ---- single exchange: per-wave totals -> later-wave carry ----
    if (q == 0) {
        red[wv][l15] = run0;
        red[wv][16 + l15] = run1;
    }
    __syncthreads();
    float c0 = 0.f, c1 = 0.f;
    #pragma unroll
    for (int w2 = 0; w2 < 8; ++w2) {
        if (w2 > wv) {
            c0 += red[w2][l15];
            c1 += red[w2][16 + l15];
        }
    }

    // ---- final store burst ----
    #pragma unroll
    for (int si = 0; si < 8; ++si) {
        const int st = 7 - si;
        const size_t eoff = (size_t)st * 16 * E_;
        float iv[4];
        #pragma unroll
        for (int r = 0; r < 4; ++r)
            iv[r] = ivLds[wv * 128 + st * 16 + q * 4 + r];
        #pragma unroll
        for (int r = 0; r < 4; ++r) {
            T0[eoff + (size_t)r * E_] = (sv0[si][r] + c0) * iv[r];
            T1[eoff + (size_t)r * E_] = (sv1[si][r] + c1) * iv[r];
        }
    }
}

extern "C" void kernel_launch(void* const* d_in, const int* in_sizes, int n_in,
                              void* d_out, int out_size, void* d_ws, size_t ws_size,
                              hipStream_t stream) {
    const float* alpha = (const float*)d_in[0];
    const float* beta  = (const float*)d_in[1];
    const float* embed = (const float*)d_in[2];
    const float* mask  = (const float*)d_in[3];
    const float* Wb    = (const float*)d_in[4];
    const float* bbp   = (const float*)d_in[5];
    const float* Wa    = (const float*)d_in[6];
    const float* bap   = (const float*)d_in[7];

    char* ws = (char*)d_ws;
    float*  w    = (float*)ws;                    // 256 KB
    __bf16* WbBf = (__bf16*)(ws + (256 << 10));   // 128 KB

    k0_prep<<<B_ * S_ / 128, 256, 0, stream>>>(alpha, mask, Wa, bap, Wb, WbBf, w);
    k2_main<<<B_ * (E_ / EG_), 512, 0, stream>>>(beta, embed, WbBf, bbp, w,
                                                 (float*)d_out);
}